// Round 1
// baseline (225.690 us; speedup 1.0000x reference)
//
#include <hip/hip_runtime.h>
#include <hip/hip_bf16.h>

// Problem constants (fixed by reference setup_inputs)
#define NIMG   16
#define CTOT   4096
#define HW     676         // 26*26
#define MTOT   (NIMG*HW)   // 10816 = 169 * 64
#define ROOTN  512
#define PPB    64          // positions per block (one per lane)
#define NBLK   (MTOT/PPB)  // 169
#define CH_PER_WAVE (ROOTN/4)  // 128

// Kernel A: per-position root-group exp-sum (4 waves split channels) +
// child-group softmax + logp accumulation. One partial sum per block -> ws.
__global__ __launch_bounds__(256) void tree_loss_main(
    const float* __restrict__ x,
    const int*   __restrict__ label,
    const int*   __restrict__ group_offsets,
    const int*   __restrict__ group_sizes,
    const int*   __restrict__ cid_groups,
    const int*   __restrict__ parents,
    float*       __restrict__ ws)
{
    __shared__ float red[4][64];

    const int tid  = threadIdx.x;
    const int lane = tid & 63;
    const int wave = tid >> 6;

    const int m = blockIdx.x * PPB + lane;     // global position in [0, MTOT)
    const int n = m / HW;
    // flat index of x[n, c, h, w] = c*HW + (m + n*HW*(CTOT-1))
    const float* xb = x + (m + n * (HW * (CTOT - 1)));

    // --- root group: sum of exp over this wave's 128-channel slice ---
    const int c0 = wave * CH_PER_WAVE;
    float a0 = 0.f, a1 = 0.f, a2 = 0.f, a3 = 0.f;
    #pragma unroll 8
    for (int cc = 0; cc < CH_PER_WAVE; cc += 4) {
        float v0 = xb[(c0 + cc + 0) * HW];
        float v1 = xb[(c0 + cc + 1) * HW];
        float v2 = xb[(c0 + cc + 2) * HW];
        float v3 = xb[(c0 + cc + 3) * HW];
        a0 += __expf(v0);
        a1 += __expf(v1);
        a2 += __expf(v2);
        a3 += __expf(v3);
    }
    red[wave][lane] = (a0 + a1) + (a2 + a3);
    __syncthreads();

    if (wave == 0) {
        float rsum = (red[0][lane] + red[1][lane]) + (red[2][lane] + red[3][lane]);

        const int lab = label[m];
        const int g   = cid_groups[lab];

        float loss_m = 0.f;
        int troot = lab;
        if (g != 0) {
            // child group softmax (size 7 here; use arrays for safety)
            const int off = group_offsets[g];
            const int sz  = group_sizes[g];
            float csum = 0.f;
            float xlab = 0.f;
            for (int j = 0; j < sz; ++j) {
                float v = xb[(off + j) * HW];
                csum += __expf(v);
                if (off + j == lab) xlab = v;
            }
            loss_m += xlab - __logf(csum);
            troot = parents[lab];
        }
        // root-group log-prob of the chain's root node
        loss_m += xb[troot * HW] - __logf(rsum);

        // wave-level reduction (64 lanes)
        #pragma unroll
        for (int d = 32; d > 0; d >>= 1)
            loss_m += __shfl_down(loss_m, d, 64);
        if (lane == 0) ws[blockIdx.x] = loss_m;
    }
}

// Kernel B: reduce the per-block partials, negate, normalize by N.
__global__ __launch_bounds__(256) void tree_loss_final(
    const float* __restrict__ ws, float* __restrict__ out)
{
    __shared__ float sm[256];
    const int t = threadIdx.x;
    float v = 0.f;
    for (int i = t; i < NBLK; i += 256) v += ws[i];
    sm[t] = v;
    __syncthreads();
    #pragma unroll
    for (int s = 128; s > 0; s >>= 1) {
        if (t < s) sm[t] += sm[t + s];
        __syncthreads();
    }
    if (t == 0) out[0] = -sm[0] * (1.0f / (float)NIMG);
}

extern "C" void kernel_launch(void* const* d_in, const int* in_sizes, int n_in,
                              void* d_out, int out_size, void* d_ws, size_t ws_size,
                              hipStream_t stream)
{
    const float* x             = (const float*)d_in[0];
    const int*   label         = (const int*)d_in[1];
    const int*   group_offsets = (const int*)d_in[2];
    const int*   group_sizes   = (const int*)d_in[3];
    const int*   cid_groups    = (const int*)d_in[4];
    const int*   parents       = (const int*)d_in[5];
    float*       out           = (float*)d_out;
    float*       ws            = (float*)d_ws;

    tree_loss_main<<<NBLK, 256, 0, stream>>>(x, label, group_offsets, group_sizes,
                                             cid_groups, parents, ws);
    tree_loss_final<<<1, 256, 0, stream>>>(ws, out);
}

// Round 2
// 225.328 us; speedup vs baseline: 1.0016x; 1.0016x over previous
//
#include <hip/hip_runtime.h>
#include <hip/hip_bf16.h>

// Problem constants (fixed by reference setup_inputs)
#define NIMG   16
#define CTOT   4096
#define HW     676            // 26*26
#define MTOT   (NIMG*HW)      // 10816 = 169 * 64
#define ROOTN  512
#define NSLICE 4              // channel slices of the root group
#define CH_PER_SLICE (ROOTN/NSLICE)   // 128
#define CH_PER_WAVE  (CH_PER_SLICE/4) // 32
#define PPB    64             // positions per block (one per lane)
#define NPB    (MTOT/PPB)     // 169 position groups
// ws layout (floats): [0, 4*MTOT) root exp-sum partials (slice-major),
//                     [4*MTOT, 4*MTOT+NPB) per-block loss partials
#define WS_BLK (NSLICE*MTOT)

// Kernel A: root-group partial exp-sums.
// grid = NSLICE*NPB blocks; block (s, pb) covers channels [128s,128s+128)
// for positions [64pb, 64pb+64). Lane <-> position (coalesced 256B loads),
// 32 fully-unrolled loads per lane = one HBM latency batch.
__global__ __launch_bounds__(256) void tree_root_partial(
    const float* __restrict__ x, float* __restrict__ ws)
{
    __shared__ float red[4][64];
    const int lane = threadIdx.x & 63;
    const int wave = threadIdx.x >> 6;
    const int s    = blockIdx.x & 3;
    const int pb   = blockIdx.x >> 2;
    const int m    = pb * PPB + lane;
    const int n    = m / HW;
    const float* xb = x + (size_t)m + (size_t)n * (HW * (CTOT - 1));

    const int c0 = s * CH_PER_SLICE + wave * CH_PER_WAVE;
    float a0 = 0.f, a1 = 0.f, a2 = 0.f, a3 = 0.f;
    #pragma unroll
    for (int cc = 0; cc < CH_PER_WAVE; cc += 4) {
        float v0 = xb[(size_t)(c0 + cc + 0) * HW];
        float v1 = xb[(size_t)(c0 + cc + 1) * HW];
        float v2 = xb[(size_t)(c0 + cc + 2) * HW];
        float v3 = xb[(size_t)(c0 + cc + 3) * HW];
        a0 += __expf(v0);
        a1 += __expf(v1);
        a2 += __expf(v2);
        a3 += __expf(v3);
    }
    red[wave][lane] = (a0 + a1) + (a2 + a3);
    __syncthreads();
    if (wave == 0) {
        float r = (red[0][lane] + red[1][lane]) + (red[2][lane] + red[3][lane]);
        ws[s * MTOT + m] = r;   // coalesced per slice
    }
}

// Kernel B: per-position loss. One wave per block, lane <-> position.
// Combines the 4 root partials (4 coalesced loads), does the 7-wide child
// group softmax (scattered, L2/HBM-latency bound), wave-reduces.
__global__ __launch_bounds__(64) void tree_loss_pos(
    const float* __restrict__ x,
    const int*   __restrict__ label,
    const int*   __restrict__ group_offsets,
    const int*   __restrict__ group_sizes,
    const int*   __restrict__ cid_groups,
    const int*   __restrict__ parents,
    float*       __restrict__ ws)
{
    const int lane = threadIdx.x;
    const int m    = blockIdx.x * PPB + lane;
    const int n    = m / HW;
    const float* xb = x + (size_t)m + (size_t)n * (HW * (CTOT - 1));

    // independent loads issued up front
    const float p0 = ws[0 * MTOT + m];
    const float p1 = ws[1 * MTOT + m];
    const float p2 = ws[2 * MTOT + m];
    const float p3 = ws[3 * MTOT + m];
    const int lab = label[m];
    const int g   = cid_groups[lab];

    float loss = 0.f;
    int troot = lab;
    if (g != 0) {
        const int off = group_offsets[g];
        const int sz  = group_sizes[g];
        float csum = 0.f, xlab = 0.f;
        for (int j = 0; j < sz; ++j) {
            float v = xb[(size_t)(off + j) * HW];
            csum += __expf(v);
            if (off + j == lab) xlab = v;
        }
        loss += xlab - __logf(csum);
        troot = parents[lab];
    }
    const float rsum = (p0 + p1) + (p2 + p3);
    loss += xb[(size_t)troot * HW] - __logf(rsum);

    #pragma unroll
    for (int d = 32; d > 0; d >>= 1)
        loss += __shfl_down(loss, d, 64);
    if (lane == 0) ws[WS_BLK + blockIdx.x] = loss;
}

// Kernel C: reduce NPB per-block partials, negate, normalize by N.
__global__ __launch_bounds__(256) void tree_loss_final(
    const float* __restrict__ ws, float* __restrict__ out)
{
    __shared__ float sm[256];
    const int t = threadIdx.x;
    float v = 0.f;
    for (int i = t; i < NPB; i += 256) v += ws[WS_BLK + i];
    sm[t] = v;
    __syncthreads();
    #pragma unroll
    for (int s = 128; s > 0; s >>= 1) {
        if (t < s) sm[t] += sm[t + s];
        __syncthreads();
    }
    if (t == 0) out[0] = -sm[0] * (1.0f / (float)NIMG);
}

extern "C" void kernel_launch(void* const* d_in, const int* in_sizes, int n_in,
                              void* d_out, int out_size, void* d_ws, size_t ws_size,
                              hipStream_t stream)
{
    const float* x             = (const float*)d_in[0];
    const int*   label         = (const int*)d_in[1];
    const int*   group_offsets = (const int*)d_in[2];
    const int*   group_sizes   = (const int*)d_in[3];
    const int*   cid_groups    = (const int*)d_in[4];
    const int*   parents       = (const int*)d_in[5];
    float*       out           = (float*)d_out;
    float*       ws            = (float*)d_ws;

    tree_root_partial<<<NSLICE * NPB, 256, 0, stream>>>(x, ws);
    tree_loss_pos<<<NPB, 64, 0, stream>>>(x, label, group_offsets, group_sizes,
                                          cid_groups, parents, ws);
    tree_loss_final<<<1, 256, 0, stream>>>(ws, out);
}